// Round 5
// baseline (2087.572 us; speedup 1.0000x reference)
//
#include <hip/hip_runtime.h>
#include <stdint.h>

#define NB 256          // batch
#define NH 1024         // hidden
#define NPOSE 135
#define NPPAD 160       // pose padded to 160
#define NSTEPS 143      // 119 encoder + 24 decoder cell steps
#define NDEC 24
#define KTOT 1184       // 1024 (h) + 160 (x padded)
#define LSTR 168        // LDS row stride in elems
#define NWG 256

typedef __bf16 bf16;
typedef __attribute__((ext_vector_type(8))) __bf16 bf16x8;
typedef __attribute__((ext_vector_type(4))) float f32x4;
typedef __attribute__((ext_vector_type(4))) uint32_t u32x4;

// ---- ws layout (bytes) ----
#define WCAT_OFF 0
#define WCAT_BYTES (4096l * KTOT * 2)
#define WFC_OFF  (WCAT_OFF + WCAT_BYTES)
#define WFC_BYTES (144l * 1024 * 2)
#define X_OFF    (WFC_OFF + WFC_BYTES)
#define X_BYTES  (143l * NB * NPPAD * 2)
#define H_OFF    (X_OFF + X_BYTES)
#define H_BYTES  (2l * NB * NH * 2)
#define BAR_OFF  (H_OFF + H_BYTES)
#define BAR_BYTES 16384
// bar ints, one counter per 128B line:
//   cnt[bb][ch]  at bar[(bb*8+ch)*32]   (h-chunk ready; +8 per step)
//   xcnt[bb]     at bar[(32+bb)*32]     (decoder X ready; +4 per out step)

// ---- LLC-coherent (L1/L2-bypass) ops: cross-XCD data WITHOUT fences ----
__device__ __forceinline__ u32x4 llc_ld16(const void* p) {
  u32x4 v;
  asm volatile("global_load_dwordx4 %0, %1, off sc0 sc1"
               : "=v"(v) : "v"(p) : "memory");
  return v;
}
__device__ __forceinline__ u32x4 g_ld16(const void* p) {   // cached (L2-resident W/X)
  u32x4 v;
  asm volatile("global_load_dwordx4 %0, %1, off"
               : "=v"(v) : "v"(p) : "memory");
  return v;
}
__device__ __forceinline__ void llc_st2(void* p, uint32_t v) {
  asm volatile("global_store_short %0, %1, off sc0 sc1"
               :: "v"(p), "v"(v) : "memory");
}
__device__ __forceinline__ void wait_vm(int n) {
  switch (n) {
    case 0:  asm volatile("s_waitcnt vmcnt(0)"  ::: "memory"); break;
    case 4:  asm volatile("s_waitcnt vmcnt(4)"  ::: "memory"); break;
    case 8:  asm volatile("s_waitcnt vmcnt(8)"  ::: "memory"); break;
    case 10: asm volatile("s_waitcnt vmcnt(10)" ::: "memory"); break;
    default: asm volatile("s_waitcnt vmcnt(0)"  ::: "memory"); break;
  }
  __builtin_amdgcn_sched_barrier(0);     // rule #18: pin consumers after the wait
}
#define POLL(ptr, tgt) do { \
    while (__hip_atomic_load((ptr), __ATOMIC_RELAXED, __HIP_MEMORY_SCOPE_AGENT) < (tgt)) \
      __builtin_amdgcn_s_sleep(1); \
  } while (0)

__global__ void k_zero(uint32_t* p, int n) {
  int i = blockIdx.x * blockDim.x + threadIdx.x;
  int st = gridDim.x * blockDim.x;
  for (; i < n; i += st) p[i] = 0u;
}

__global__ void k_wcat(const float* __restrict__ Whh, const float* __restrict__ Wih,
                       bf16* __restrict__ W) {
  int n = blockIdx.x;
  for (int kk = threadIdx.x; kk < KTOT; kk += blockDim.x) {
    float v = 0.f;
    if (kk < NH) v = Whh[(size_t)n * NH + kk];
    else if (kk - NH < NPOSE) v = Wih[(size_t)n * NPOSE + (kk - NH)];
    W[(size_t)n * KTOT + kk] = (bf16)v;
  }
}

__global__ void k_wfc(const float* __restrict__ Wfc, bf16* __restrict__ W) {
  int p = blockIdx.x;
  for (int kk = threadIdx.x; kk < NH; kk += blockDim.x) {
    float v = (p < NPOSE) ? Wfc[(size_t)p * NH + kk] : 0.f;
    W[(size_t)p * NH + kk] = (bf16)v;
  }
}

__global__ void k_x(const float* __restrict__ poses, bf16* __restrict__ X) {
  int idx = blockIdx.x;          // t*256 + b, t in [0,120)
  int t = idx >> 8, b = idx & 255;
  int p = threadIdx.x;
  if (p < NPPAD) {
    float v = (p < NPOSE) ? poses[((size_t)b * 144 + t) * NPOSE + p] : 0.f;
    X[(size_t)idx * NPPAD + p] = (bf16)v;
  }
}

__device__ __forceinline__ float sigm(float x) { return 1.f / (1.f + __expf(-x)); }
__device__ __forceinline__ float tanh_(float x) {
  float e = __expf(2.f * x);
  return 1.f - 2.f / (e + 1.f);
}

__global__ __launch_bounds__(256) void
k_main(const float* __restrict__ poses, const float* __restrict__ bfc,
       const bf16* __restrict__ Wcat, const bf16* __restrict__ Wfcb,
       bf16* __restrict__ X, bf16* __restrict__ H, int* __restrict__ bar,
       float* __restrict__ out) {
  __shared__ bf16 Alds[2 * 64 * LSTR];
  __shared__ bf16 Blds[2 * 64 * LSTR];
  const int tid  = threadIdx.x;
  const int lane = tid & 63;
  const int wv   = tid >> 6;
  const int cl   = lane & 15;
  const int quad = lane >> 4;
  const int L    = blockIdx.x;
  const int jb = (L & 7) * 8 + ((L >> 3) & 7);   // XCD-aware j-block
  const int bb = L >> 6;                          // dataflow group (batch block)
  const int b0 = bb * 64;
  const int j0 = jb * 16;
  const int mych = jb >> 3;                       // h-chunk this WG produces
  const bool is_out = (L & 63) < 4;               // out-phase WGs, group-local
  const int brow0 = bb * 64 + (L & 3) * 16;       // out rows [brow0, brow0+16)

  // ---- precomputed per-thread offsets ----
  const int rA  = tid >> 4;
  const int iu8 = (tid & 15) * 8;
  int offA[4], offB[4], offL[4];
  #pragma unroll
  for (int it = 0; it < 4; ++it) {
    offA[it] = (rA + it * 16) * NH + iu8;
    offB[it] = (it * NH + j0 + rA) * KTOT + iu8;
    offL[it] = (rA + it * 16) * LSTR + iu8;
  }
  int o8x[5], o8w[5], o8l[5];
  #pragma unroll
  for (int it = 0; it < 5; ++it) {
    int u = tid + it * 256, r = u / 20, iu = u % 20;
    o8x[it] = r * NPPAD + iu * 8;
    o8w[it] = ((r >> 4) * NH + j0 + (r & 15)) * KTOT + 1024 + iu * 8;
    o8l[it] = r * LSTR + iu * 8;
  }
  const int aoff = (wv * 16 + cl) * LSTR + quad * 8;
  const int boff = cl * LSTR + quad * 8;

  u32x4 ar0[5], br0[5], ar1[5], br1[5];
  float cst[4] = {0.f, 0.f, 0.f, 0.f};
  f32x4 acc0, acc1, acc2, acc3;

#define ISSUE_BH(BR, chn) do { const bf16* gb_ = Wcat + (size_t)(chn) * 128; \
    BR[0] = g_ld16(gb_ + offB[0]); BR[1] = g_ld16(gb_ + offB[1]); \
    BR[2] = g_ld16(gb_ + offB[2]); BR[3] = g_ld16(gb_ + offB[3]); } while (0)
#define ISSUE_AH(AR, HP, chn) do { const bf16* ga_ = (HP) + (size_t)b0 * NH + (chn) * 128; \
    AR[0] = llc_ld16(ga_ + offA[0]); AR[1] = llc_ld16(ga_ + offA[1]); \
    AR[2] = llc_ld16(ga_ + offA[2]); AR[3] = llc_ld16(ga_ + offA[3]); } while (0)
#define ISSUE_XC(AR, BR, sv) do { const bf16* ga_ = X + ((size_t)(sv) * NB + b0) * NPPAD; \
    if ((sv) < 120) { \
      AR[0] = g_ld16(ga_ + o8x[0]); AR[1] = g_ld16(ga_ + o8x[1]); AR[2] = g_ld16(ga_ + o8x[2]); \
      AR[3] = g_ld16(ga_ + o8x[3]); AR[4] = g_ld16(ga_ + o8x[4]); \
    } else { \
      AR[0] = llc_ld16(ga_ + o8x[0]); AR[1] = llc_ld16(ga_ + o8x[1]); AR[2] = llc_ld16(ga_ + o8x[2]); \
      AR[3] = llc_ld16(ga_ + o8x[3]); AR[4] = llc_ld16(ga_ + o8x[4]); \
    } \
    BR[0] = g_ld16(Wcat + o8w[0]); BR[1] = g_ld16(Wcat + o8w[1]); BR[2] = g_ld16(Wcat + o8w[2]); \
    BR[3] = g_ld16(Wcat + o8w[3]); BR[4] = g_ld16(Wcat + o8w[4]); } while (0)
#define WRITEL4(AR, BR, p) do { \
    bf16* Al_ = &Alds[(p) * 64 * LSTR]; bf16* Bl_ = &Blds[(p) * 64 * LSTR]; \
    *(u32x4*)&Al_[offL[0]] = AR[0]; *(u32x4*)&Bl_[offL[0]] = BR[0]; \
    *(u32x4*)&Al_[offL[1]] = AR[1]; *(u32x4*)&Bl_[offL[1]] = BR[1]; \
    *(u32x4*)&Al_[offL[2]] = AR[2]; *(u32x4*)&Bl_[offL[2]] = BR[2]; \
    *(u32x4*)&Al_[offL[3]] = AR[3]; *(u32x4*)&Bl_[offL[3]] = BR[3]; } while (0)
#define WRITEL5(AR, BR, p) do { \
    bf16* Al_ = &Alds[(p) * 64 * LSTR]; bf16* Bl_ = &Blds[(p) * 64 * LSTR]; \
    *(u32x4*)&Al_[o8l[0]] = AR[0]; *(u32x4*)&Bl_[o8l[0]] = BR[0]; \
    *(u32x4*)&Al_[o8l[1]] = AR[1]; *(u32x4*)&Bl_[o8l[1]] = BR[1]; \
    *(u32x4*)&Al_[o8l[2]] = AR[2]; *(u32x4*)&Bl_[o8l[2]] = BR[2]; \
    *(u32x4*)&Al_[o8l[3]] = AR[3]; *(u32x4*)&Bl_[o8l[3]] = BR[3]; \
    *(u32x4*)&Al_[o8l[4]] = AR[4]; *(u32x4*)&Bl_[o8l[4]] = BR[4]; } while (0)
#define MFMAP(p, nks) do { \
    const bf16* Al_ = &Alds[(p) * 64 * LSTR]; const bf16* Bl_ = &Blds[(p) * 64 * LSTR]; \
    _Pragma("unroll") \
    for (int ks = 0; ks < (nks); ++ks) { \
      bf16x8 af  = *(const bf16x8*)&Al_[aoff + ks * 32]; \
      bf16x8 b0f = *(const bf16x8*)&Bl_[boff + ks * 32]; \
      bf16x8 b1f = *(const bf16x8*)&Bl_[boff + 16 * LSTR + ks * 32]; \
      bf16x8 b2f = *(const bf16x8*)&Bl_[boff + 32 * LSTR + ks * 32]; \
      bf16x8 b3f = *(const bf16x8*)&Bl_[boff + 48 * LSTR + ks * 32]; \
      acc0 = __builtin_amdgcn_mfma_f32_16x16x32_bf16(af, b0f, acc0, 0, 0, 0); \
      acc1 = __builtin_amdgcn_mfma_f32_16x16x32_bf16(af, b1f, acc1, 0, 0, 0); \
      acc2 = __builtin_amdgcn_mfma_f32_16x16x32_bf16(af, b2f, acc2, 0, 0, 0); \
      acc3 = __builtin_amdgcn_mfma_f32_16x16x32_bf16(af, b3f, acc3, 0, 0, 0); \
    } } while (0)

  // ---- prologue: chunks 0,1 of step 0 (h(0)=zeros; counters at 0, no poll) ----
  ISSUE_BH(br0, 0); ISSUE_BH(br1, 1);
  ISSUE_AH(ar0, H, 0); ISSUE_AH(ar1, H, 1);

  for (int s = 0; s < NSTEPS; ++s) {
    const bf16* Hr = H + (size_t)(s & 1) * (NB * NH);
    bf16* Hw = H + (size_t)((s + 1) & 1) * (NB * NH);
    acc0 = f32x4{0,0,0,0}; acc1 = f32x4{0,0,0,0};
    acc2 = f32x4{0,0,0,0}; acc3 = f32x4{0,0,0,0};

    #pragma unroll
    for (int ch = 0; ch < 8; ++ch) {
      wait_vm(ch == 0 ? 4 : (ch == 7 ? 10 : 8));   // counted: keep next chunk in flight
      if ((ch & 1) == 0) { WRITEL4(ar0, br0, 0); } else { WRITEL4(ar1, br1, 1); }
      __syncthreads();
      if (ch < 6) {                                // issue chunk ch+2 (depth 2)
        POLL(&bar[(bb * 8 + ch + 2) * 32], 8 * s);
        if ((ch & 1) == 0) { ISSUE_BH(br0, ch + 2); ISSUE_AH(ar0, Hr, ch + 2); }
        else               { ISSUE_BH(br1, ch + 2); ISSUE_AH(ar1, Hr, ch + 2); }
      } else if (ch == 6) {                        // issue x-chunk
        if (s >= 120) POLL(&bar[(32 + bb) * 32], 4 * (s - 119));
        ISSUE_XC(ar0, br0, s);
      }
      MFMAP(ch & 1, 4);
    }
    wait_vm(0);                                    // x-chunk arrived
    WRITEL5(ar0, br0, 0);
    __syncthreads();
    if (s + 1 < NSTEPS) { ISSUE_BH(br0, 0); ISSUE_BH(br1, 1); }  // W is step-invariant
    MFMAP(0, 5);

    // ---- activations + h-store (bypass) + ready-signal ----
    #pragma unroll
    for (int r = 0; r < 4; ++r) {
      float gi = sigm(acc0[r]);
      float gf = sigm(acc1[r]);
      float gg = tanh_(acc2[r]);
      float go = sigm(acc3[r]);
      float cn = gf * cst[r] + gi * gg;
      cst[r] = cn;
      float h = go * tanh_(cn);
      bf16 hb = (bf16)h;
      llc_st2(&Hw[(size_t)(b0 + wv * 16 + quad * 4 + r) * NH + j0 + cl],
              (uint32_t)__builtin_bit_cast(uint16_t, hb));
    }
    wait_vm(0);                                    // h-tile acked at LLC
    if (tid == 0) atomicAdd(&bar[(bb * 8 + mych) * 32], 1);
    __syncthreads();                               // no wave may touch buf0 before all done ch8-mfma

    if (s >= 119 && is_out) {   // decoder out = inp + h_new @ W_fc^T + b_fc (group-local WGs)
      const int k = s - 119;
      #pragma unroll
      for (int ch = 0; ch < 8; ++ch)               // need full h(s+1) for our rows
        POLL(&bar[(bb * 8 + ch) * 32], 8 * (s + 1));
      f32x4 oa[3] = {{0,0,0,0},{0,0,0,0},{0,0,0,0}};
      const bf16* hrow = Hw + (size_t)(brow0 + cl) * NH;
      for (int kb = 0; kb < 4; ++kb) {
        u32x4 hv[8];
        #pragma unroll
        for (int t = 0; t < 8; ++t)
          hv[t] = llc_ld16(&hrow[(kb * 8 + t) * 32 + quad * 8]);
        wait_vm(0);
        #pragma unroll
        for (int t = 0; t < 8; ++t) {
          bf16x8 af = __builtin_bit_cast(bf16x8, hv[t]);
          #pragma unroll
          for (int i = 0; i < 3; ++i) {
            int ct = wv + i * 4;
            if (ct > 8) continue;
            bf16x8 bw = *(const bf16x8*)&Wfcb[(size_t)(ct * 16 + cl) * NH
                                              + (kb * 8 + t) * 32 + quad * 8];
            oa[i] = __builtin_amdgcn_mfma_f32_16x16x32_bf16(af, bw, oa[i], 0, 0, 0);
          }
        }
      }
      #pragma unroll
      for (int i = 0; i < 3; ++i) {
        int ct = wv + i * 4;
        if (ct > 8) continue;
        int p = ct * 16 + cl;
        if (p < NPOSE) {
          #pragma unroll
          for (int r = 0; r < 4; ++r) {
            int b = brow0 + quad * 4 + r;
            float inp = (k == 0) ? poses[((size_t)b * 144 + 119) * NPOSE + p]
                                 : out[((size_t)b * NDEC + (k - 1)) * NPOSE + p];
            float v = oa[i][r] + inp + bfc[p];     // additive chain kept fp32
            out[((size_t)b * NDEC + k) * NPOSE + p] = v;
            if (s + 1 < NSTEPS) {
              bf16 xb = (bf16)v;
              llc_st2(&X[((size_t)(s + 1) * NB + b) * NPPAD + p],
                      (uint32_t)__builtin_bit_cast(uint16_t, xb));
            }
          }
        }
      }
      if (s + 1 < NSTEPS) {
        wait_vm(0);                                // X(s+1) acked at LLC
        if (tid == 0) atomicAdd(&bar[(32 + bb) * 32], 1);
      }
    }

    // ---- tail: issue chunks 0,1 of step s+1 (gated on h(s+1) readiness) ----
    if (s + 1 < NSTEPS) {
      POLL(&bar[(bb * 8 + 0) * 32], 8 * (s + 1));
      ISSUE_AH(ar0, Hw, 0);
      POLL(&bar[(bb * 8 + 1) * 32], 8 * (s + 1));
      ISSUE_AH(ar1, Hw, 1);
    }
  }
}

extern "C" void kernel_launch(void* const* d_in, const int* in_sizes, int n_in,
                              void* d_out, int out_size, void* d_ws, size_t ws_size,
                              hipStream_t stream) {
  const float* poses = (const float*)d_in[0];
  const float* Wih   = (const float*)d_in[1];
  const float* Whh   = (const float*)d_in[2];
  const float* Wfc   = (const float*)d_in[3];
  const float* bfc   = (const float*)d_in[4];
  if (ws_size < (size_t)(BAR_OFF + BAR_BYTES)) return;

  char* ws = (char*)d_ws;
  bf16* Wcat = (bf16*)(ws + WCAT_OFF);
  bf16* Wfcb = (bf16*)(ws + WFC_OFF);
  bf16* X    = (bf16*)(ws + X_OFF);
  bf16* H    = (bf16*)(ws + H_OFF);
  int*  bar  = (int*)(ws + BAR_OFF);

  k_zero<<<256, 256, 0, stream>>>((uint32_t*)(ws + H_OFF), (int)((H_BYTES + BAR_BYTES) / 4));
  k_zero<<<256, 256, 0, stream>>>((uint32_t*)(X + (size_t)120 * NB * NPPAD),
                                  (int)(23l * NB * NPPAD * 2 / 4));
  k_wcat<<<4096, 256, 0, stream>>>(Whh, Wih, Wcat);
  k_wfc<<<144, 256, 0, stream>>>(Wfc, Wfcb);
  k_x<<<120 * 256, 256, 0, stream>>>(poses, X);
  k_main<<<NWG, 256, 0, stream>>>(poses, bfc, Wcat, Wfcb, X, H, bar, (float*)d_out);
}

// Round 7
// 1643.901 us; speedup vs baseline: 1.2699x; 1.2699x over previous
//
#include <hip/hip_runtime.h>
#include <stdint.h>

#define NB 256          // batch
#define NH 1024         // hidden
#define NPOSE 135
#define NPPAD 160       // pose padded to 160
#define NSTEPS 143      // 119 encoder + 24 decoder cell steps
#define NDEC 24
#define KTOT 1184       // 1024 (h) + 160 (x padded)
#define LSTR 168        // LDS row stride for x-B chunk
#define NWG 256

typedef __bf16 bf16;
typedef __attribute__((ext_vector_type(8))) __bf16 bf16x8;
typedef __attribute__((ext_vector_type(4))) float f32x4;
typedef __attribute__((ext_vector_type(4))) uint32_t u32x4;

// ---- ws layout (bytes) ----
#define WCAT_OFF 0
#define WCAT_BYTES (4096l * KTOT * 2)
#define WFC_OFF  (WCAT_OFF + WCAT_BYTES)
#define WFC_BYTES (144l * 1024 * 2)
#define X_OFF    (WFC_OFF + WFC_BYTES)
#define X_BYTES  (143l * NB * NPPAD * 2)
#define H_OFF    (X_OFF + X_BYTES)
#define H_BYTES  (2l * NB * NH * 2)
#define BAR_OFF  (H_OFF + H_BYTES)
#define BAR_BYTES 16384
// bar ints, one counter per 128B line:
//   cnt[bb][ch] at bar[(bb*8+ch)*32]  (h-chunk ready; 8 producers, +8/step)
//   xcnt[bb]    at bar[(32+bb)*32]    (decoder X ready; +4/out-step)

// ---- LLC-coherent (L1/L2-bypass) ops: cross-XCD data WITHOUT fences ----
// NOTE: deferred-waitcnt asm loads require LOW register pressure — the
// compiler may spill/reuse an in-flight dest under pressure (r6 crash).
__device__ __forceinline__ u32x4 llc_ld16(const void* p) {
  u32x4 v;
  asm volatile("global_load_dwordx4 %0, %1, off sc0 sc1"
               : "=v"(v) : "v"(p) : "memory");
  return v;
}
__device__ __forceinline__ u32x4 g_ld16(const void* p) {   // cached, vmcnt-tracked
  u32x4 v;
  asm volatile("global_load_dwordx4 %0, %1, off"
               : "=v"(v) : "v"(p) : "memory");
  return v;
}
__device__ __forceinline__ void llc_st2(void* p, uint32_t v) {
  asm volatile("global_store_short %0, %1, off sc0 sc1"
               :: "v"(p), "v"(v) : "memory");
}
#define WAIT_VM(n) do { \
    asm volatile("s_waitcnt vmcnt(" #n ")" ::: "memory"); \
    __builtin_amdgcn_sched_barrier(0); } while (0)

#define POLL(ptr, tgt) do { \
    while (__hip_atomic_load((ptr), __ATOMIC_RELAXED, __HIP_MEMORY_SCOPE_AGENT) < (tgt)) \
      __builtin_amdgcn_s_sleep(1); \
  } while (0)

__global__ void k_zero(uint32_t* p, int n) {
  int i = blockIdx.x * blockDim.x + threadIdx.x;
  int st = gridDim.x * blockDim.x;
  for (; i < n; i += st) p[i] = 0u;
}

__global__ void k_wcat(const float* __restrict__ Whh, const float* __restrict__ Wih,
                       bf16* __restrict__ W) {
  int n = blockIdx.x;
  for (int kk = threadIdx.x; kk < KTOT; kk += blockDim.x) {
    float v = 0.f;
    if (kk < NH) v = Whh[(size_t)n * NH + kk];
    else if (kk - NH < NPOSE) v = Wih[(size_t)n * NPOSE + (kk - NH)];
    W[(size_t)n * KTOT + kk] = (bf16)v;
  }
}

__global__ void k_wfc(const float* __restrict__ Wfc, bf16* __restrict__ W) {
  int p = blockIdx.x;
  for (int kk = threadIdx.x; kk < NH; kk += blockDim.x) {
    float v = (p < NPOSE) ? Wfc[(size_t)p * NH + kk] : 0.f;
    W[(size_t)p * NH + kk] = (bf16)v;
  }
}

__global__ void k_x(const float* __restrict__ poses, bf16* __restrict__ X) {
  int idx = blockIdx.x;          // t*256 + b, t in [0,120)
  int t = idx >> 8, b = idx & 255;
  int p = threadIdx.x;
  if (p < NPPAD) {
    float v = (p < NPOSE) ? poses[((size_t)b * 144 + t) * NPOSE + p] : 0.f;
    X[(size_t)idx * NPPAD + p] = (bf16)v;
  }
}

__device__ __forceinline__ float sigm(float x) { return 1.f / (1.f + __expf(-x)); }
__device__ __forceinline__ float tanh_(float x) {
  float e = __expf(2.f * x);
  return 1.f - 2.f / (e + 1.f);
}

__global__ __launch_bounds__(256, 1) void
k_main(const float* __restrict__ poses, const float* __restrict__ bfc,
       const bf16* __restrict__ Wcat, const bf16* __restrict__ Wfcb,
       bf16* __restrict__ X, bf16* __restrict__ H, int* __restrict__ bar,
       float* __restrict__ out) {
  // B is step-invariant: ALL h-chunks + x-chunk staged to LDS ONCE.
  // BldsH[c][row=gate*16+j][e]: 16B-group e stored at slot e ^ (row&15)
  // (4-bit XOR swizzle -> b128 reads are ~2-way, free).
  __shared__ bf16 BldsH[8 * 64 * 128];     // 128 KiB
  __shared__ bf16 BldsX[64 * LSTR];        // 21 KiB

  const int tid  = threadIdx.x;
  const int lane = tid & 63;
  const int wv   = tid >> 6;
  const int cl   = lane & 15;
  const int quad = lane >> 4;
  const int L    = blockIdx.x;
  const int jb = (L & 7) * 8 + ((L >> 3) & 7);   // XCD-aware j-block
  const int bb = L >> 6;                          // batch group
  const int b0 = bb * 64;
  const int j0 = jb * 16;
  const int mych = jb >> 3;                       // h-chunk this WG produces
  // out-WGs produce chunk 7 (last-needed by consumers)
  const bool is_out = ((L & 7) == 7) && (((L >> 3) & 7) < 4);
  const int brow0 = bb * 64 + ((L >> 3) & 7) * 16;

  // ---- one-time B staging (plain loads; compiler-managed waits) ----
  for (int t = tid; t < 8 * 64 * 16; t += 256) {
    int c = t >> 10, rem = t & 1023, r = rem >> 4, xb = rem & 15;
    u32x4 v = *(const u32x4*)&Wcat[(size_t)((r >> 4) * NH + j0 + (r & 15)) * KTOT
                                   + c * 128 + xb * 8];
    *(u32x4*)&BldsH[(c * 64 + r) * 128 + ((xb ^ (r & 15)) << 3)] = v;
  }
  for (int it = 0; it < 5; ++it) {
    int u = tid + it * 256, r = u / 20, iu = u % 20;
    u32x4 v = *(const u32x4*)&Wcat[(size_t)((r >> 4) * NH + j0 + (r & 15)) * KTOT
                                   + 1024 + iu * 8];
    *(u32x4*)&BldsX[r * LSTR + iu * 8] = v;
  }
  __syncthreads();

  // ---- per-lane A addressing (direct-to-fragment; A never touches LDS) ----
  const int arow = b0 + wv * 16 + cl;                 // A row this lane owns
  const size_t aBase  = (size_t)arow * NH + quad * 8; // + ch*128 (+ks*32 via imm)
  const size_t axBase = (size_t)arow * NPPAD + quad * 8;

  u32x4 A0[4], A1[4], A2[4], AX[5];
  f32x4 acc[4];
  float cst[4] = {0.f, 0.f, 0.f, 0.f};

#define ISSUE_AH(SET, HP, chn) do { \
    const bf16* ga_ = (HP) + aBase + (chn) * 128; \
    SET[0] = llc_ld16(ga_);      SET[1] = llc_ld16(ga_ + 32); \
    SET[2] = llc_ld16(ga_ + 64); SET[3] = llc_ld16(ga_ + 96); } while (0)
#define ISSUE_AX(sv) do { \
    const bf16* ga_ = X + (size_t)(sv) * NB * NPPAD + axBase; \
    if ((sv) < 120) { \
      AX[0] = g_ld16(ga_);        AX[1] = g_ld16(ga_ + 32); \
      AX[2] = g_ld16(ga_ + 64);   AX[3] = g_ld16(ga_ + 96); \
      AX[4] = g_ld16(ga_ + 128); \
    } else { \
      AX[0] = llc_ld16(ga_);      AX[1] = llc_ld16(ga_ + 32); \
      AX[2] = llc_ld16(ga_ + 64); AX[3] = llc_ld16(ga_ + 96); \
      AX[4] = llc_ld16(ga_ + 128); \
    } } while (0)
#define MFMA_LDS(SET, c) do { \
    _Pragma("unroll") \
    for (int ks = 0; ks < 4; ++ks) { \
      bf16x8 af_ = __builtin_bit_cast(bf16x8, SET[ks]); \
      _Pragma("unroll") \
      for (int gb = 0; gb < 4; ++gb) { \
        bf16x8 bw_ = *(const bf16x8*)&BldsH[((c) * 64 + gb * 16 + cl) * 128 \
                                            + (((ks * 4 + quad) ^ cl) << 3)]; \
        acc[gb] = __builtin_amdgcn_mfma_f32_16x16x32_bf16(af_, bw_, acc[gb], 0, 0, 0); \
      } } } while (0)
#define MFMA_X() do { \
    _Pragma("unroll") \
    for (int ks = 0; ks < 5; ++ks) { \
      bf16x8 af_ = __builtin_bit_cast(bf16x8, AX[ks]); \
      _Pragma("unroll") \
      for (int gb = 0; gb < 4; ++gb) { \
        bf16x8 bw_ = *(const bf16x8*)&BldsX[(gb * 16 + cl) * LSTR + ks * 32 + quad * 8]; \
        acc[gb] = __builtin_amdgcn_mfma_f32_16x16x32_bf16(af_, bw_, acc[gb], 0, 0, 0); \
      } } } while (0)
#define POLL_ALL8(tgt) do { \
    for (;;) { int ok_ = 1; \
      _Pragma("unroll") \
      for (int c_ = 0; c_ < 8; ++c_) \
        ok_ &= (__hip_atomic_load(&bar[(bb * 8 + c_) * 32], __ATOMIC_RELAXED, \
                                  __HIP_MEMORY_SCOPE_AGENT) >= (tgt)); \
      if (ok_) break; __builtin_amdgcn_s_sleep(1); } } while (0)

  // ---- prologue: A-chunks 0,1 of step 0 (h(0)=zeros) ----
  ISSUE_AH(A0, H, 0);
  ISSUE_AH(A1, H, 1);

  for (int s = 0; s < NSTEPS; ++s) {
    const bf16* Hr = H + (size_t)(s & 1) * (NB * NH);
    bf16* Hw = H + (size_t)((s + 1) & 1) * (NB * NH);
    #pragma unroll
    for (int gb = 0; gb < 4; ++gb) acc[gb] = f32x4{0, 0, 0, 0};

    // steady-state: no __syncthreads, no LDS writes; depth-2 A prefetch.
    // h(s) fully ready: gated by previous step's tail POLL_ALL8.
    ISSUE_AH(A2, Hr, 2); WAIT_VM(8); MFMA_LDS(A0, 0);
    ISSUE_AH(A0, Hr, 3); WAIT_VM(8); MFMA_LDS(A1, 1);
    ISSUE_AH(A1, Hr, 4); WAIT_VM(8); MFMA_LDS(A2, 2);
    ISSUE_AH(A2, Hr, 5); WAIT_VM(8); MFMA_LDS(A0, 3);
    ISSUE_AH(A0, Hr, 6); WAIT_VM(8); MFMA_LDS(A1, 4);
    ISSUE_AH(A1, Hr, 7); WAIT_VM(8); MFMA_LDS(A2, 5);
    if (s >= 120) POLL(&bar[(32 + bb) * 32], 4 * (s - 119));
    ISSUE_AX(s);         WAIT_VM(9); MFMA_LDS(A0, 6);
                         WAIT_VM(5); MFMA_LDS(A1, 7);
                         WAIT_VM(0); MFMA_X();

    // ---- activations + h-store (bypass) + ready signal ----
    #pragma unroll
    for (int r = 0; r < 4; ++r) {
      float gi = sigm(acc[0][r]);
      float gf = sigm(acc[1][r]);
      float gg = tanh_(acc[2][r]);
      float go = sigm(acc[3][r]);
      float cn = gf * cst[r] + gi * gg;
      cst[r] = cn;
      float h = go * tanh_(cn);
      bf16 hb = (bf16)h;
      llc_st2(&Hw[(size_t)(b0 + wv * 16 + quad * 4 + r) * NH + j0 + cl],
              (uint32_t)__builtin_bit_cast(uint16_t, hb));
    }
    WAIT_VM(0);                                     // h-tile acked at LLC
    __syncthreads();                                // all 4 waves stored
    if (tid == 0) atomicAdd(&bar[(bb * 8 + mych) * 32], 1);

    if (s >= 119 && is_out) {   // decoder: out = inp + h_new @ W_fc^T + b_fc
      const int k = s - 119;
      POLL_ALL8(8 * (s + 1));                       // full h(s+1) ready
      f32x4 oa[3] = {{0,0,0,0},{0,0,0,0},{0,0,0,0}};
      const bf16* hrow = Hw + (size_t)(brow0 + cl) * NH;
      for (int kb = 0; kb < 4; ++kb) {              // bypass h reads
        u32x4 hv[8];
        #pragma unroll
        for (int t = 0; t < 8; ++t)
          hv[t] = llc_ld16(&hrow[(kb * 8 + t) * 32 + quad * 8]);
        WAIT_VM(0);
        #pragma unroll
        for (int t = 0; t < 8; ++t) {
          bf16x8 af = __builtin_bit_cast(bf16x8, hv[t]);
          #pragma unroll
          for (int i = 0; i < 3; ++i) {
            int ct = wv + i * 4;
            if (ct > 8) continue;
            bf16x8 bw = *(const bf16x8*)&Wfcb[(size_t)(ct * 16 + cl) * NH
                                              + (kb * 8 + t) * 32 + quad * 8];
            oa[i] = __builtin_amdgcn_mfma_f32_16x16x32_bf16(af, bw, oa[i], 0, 0, 0);
          }
        }
      }
      #pragma unroll
      for (int i = 0; i < 3; ++i) {
        int ct = wv + i * 4;
        if (ct > 8) continue;
        int p = ct * 16 + cl;
        if (p < NPOSE) {
          #pragma unroll
          for (int r = 0; r < 4; ++r) {
            int b = brow0 + quad * 4 + r;
            float inp = (k == 0) ? poses[((size_t)b * 144 + 119) * NPOSE + p]
                                 : out[((size_t)b * NDEC + (k - 1)) * NPOSE + p];
            float v = oa[i][r] + inp + bfc[p];       // additive chain kept fp32
            out[((size_t)b * NDEC + k) * NPOSE + p] = v;
            if (s + 1 < NSTEPS) {
              bf16 xb = (bf16)v;
              llc_st2(&X[((size_t)(s + 1) * NB + b) * NPPAD + p],
                      (uint32_t)__builtin_bit_cast(uint16_t, xb));
            }
          }
        }
      }
      if (s + 1 < NSTEPS) {
        WAIT_VM(0);                                 // X(s+1) acked at LLC
        __syncthreads();                            // all waves stored X
        if (tid == 0) atomicAdd(&bar[(32 + bb) * 32], 1);
      }
    }

    // ---- tail: fused readiness poll, then prefetch step s+1 chunks 0,1 ----
    if (s + 1 < NSTEPS) {
      POLL_ALL8(8 * (s + 1));
      ISSUE_AH(A0, Hw, 0);
      ISSUE_AH(A1, Hw, 1);
    }
  }
}

extern "C" void kernel_launch(void* const* d_in, const int* in_sizes, int n_in,
                              void* d_out, int out_size, void* d_ws, size_t ws_size,
                              hipStream_t stream) {
  const float* poses = (const float*)d_in[0];
  const float* Wih   = (const float*)d_in[1];
  const float* Whh   = (const float*)d_in[2];
  const float* Wfc   = (const float*)d_in[3];
  const float* bfc   = (const float*)d_in[4];
  if (ws_size < (size_t)(BAR_OFF + BAR_BYTES)) return;

  char* ws = (char*)d_ws;
  bf16* Wcat = (bf16*)(ws + WCAT_OFF);
  bf16* Wfcb = (bf16*)(ws + WFC_OFF);
  bf16* X    = (bf16*)(ws + X_OFF);
  bf16* H    = (bf16*)(ws + H_OFF);
  int*  bar  = (int*)(ws + BAR_OFF);

  k_zero<<<256, 256, 0, stream>>>((uint32_t*)(ws + H_OFF), (int)((H_BYTES + BAR_BYTES) / 4));
  k_zero<<<256, 256, 0, stream>>>((uint32_t*)(X + (size_t)120 * NB * NPPAD),
                                  (int)(23l * NB * NPPAD * 2 / 4));
  k_wcat<<<4096, 256, 0, stream>>>(Whh, Wih, Wcat);
  k_wfc<<<144, 256, 0, stream>>>(Wfc, Wfcb);
  k_x<<<120 * 256, 256, 0, stream>>>(poses, X);
  k_main<<<NWG, 256, 0, stream>>>(poses, bfc, Wcat, Wfcb, X, H, bar, (float*)d_out);
}